// Round 5
// baseline (598.707 us; speedup 1.0000x reference)
//
#include <hip/hip_runtime.h>
#include <math.h>

// Soft-Viterbi structured decoding: B=32, T=512, N=128, fp32.
// Round 5: remove ALL per-step global memory traffic. Rounds 1-4 all cost
// ~1245-1370 cyc/step because every step issued a global em-prefetch load and
// an alpha-stash store, and __syncthreads() drains vmcnt(0) -> a full global
// round trip (~200-900 cyc) sat on the serial chain EVERY step.
// Fix: chunk everything through LDS, 16 steps per chunk:
//   * em chunks: cooperative 8 KB load -> embuf[2][16][128] ping-pong,
//     once per 16 steps. Per-step d = exp(em) from an off-chain LDS read,
//     register-pipelined one step ahead.
//   * alpha~ history: stash to abuf[2][16][128] (LDS), dump to out once per
//     16 steps. Backward reloads em+alpha chunks the same way (chunk 31 is
//     still LDS-resident from the forward pass - no reload), accumulates p_t
//     in pbuf[2][16][128], dumps per chunk.
//   -> vmcnt drains once per 16 steps (amortized ~25 cyc/step) instead of
//      every step.
// Dot engine unchanged from r4 (readlane broadcast, one barrier/step).
// tb fragment built AFTER the forward loop so tf/tb never both live (no spill).

#define TT 512
#define BB 32
#define NN 128
#define CH 16
#define EPSC 1e-10f

__device__ __forceinline__ float rdl(float v, int sl) {
  return __uint_as_float(__builtin_amdgcn_readlane(__float_as_uint(v), sl));
}
__device__ __forceinline__ float rcpf(float v) { return __builtin_amdgcn_rcpf(v); }

// Partial dot over one 64-state half; B = 32*h (compile-time readlane base).
template <int B>
__device__ __forceinline__ float dot_half(const float (&frag)[64], float va0, float va1) {
  float c0 = 0.f, c1 = 0.f, c2 = 0.f, c3 = 0.f;
  #pragma unroll
  for (int k = 0; k < 32; k += 2) {
    c0 = fmaf(rdl(va0, B + k),     frag[2 * k],     c0);
    c1 = fmaf(rdl(va1, B + k),     frag[2 * k + 1], c1);
    c2 = fmaf(rdl(va0, B + k + 1), frag[2 * k + 2], c2);
    c3 = fmaf(rdl(va1, B + k + 1), frag[2 * k + 3], c3);
  }
  return (c0 + c2) + (c1 + c3);
}

__global__ __launch_bounds__(256, 1)
void soft_viterbi_kernel(const float* __restrict__ trans,
                         const float* __restrict__ emis,
                         const float* __restrict__ prior,
                         float* __restrict__ out) {
  const int tid  = threadIdx.x;
  const int w    = tid >> 6;
  const int lane = tid & 63;
  const int h    = w & 1;                 // k-half this wave sums
  const int pr_  = w >> 1;                // output block
  const int n_own = 64 * pr_ + lane;
  const int ps   = lane >> 5;
  const int sl   = (2 * lane) & 63;

  __shared__ __align__(16) float part[2][2][136];
  __shared__ float sarr[TT];
  __shared__ __align__(16) float red[NN];
  __shared__ __align__(16) float embuf[2][CH][NN];  // em chunks (ping-pong by chunk&1)
  __shared__ __align__(16) float abuf[2][CH][NN];   // alpha~ chunks
  __shared__ __align__(16) float pbuf[2][CH][NN];   // p output chunks

  const float4* em4 = (const float4*)emis + (size_t)blockIdx.x * TT * (NN / 4);
  float4*       out4 = (float4*)out       + (size_t)blockIdx.x * TT * (NN / 4);

  // ---- 1/rowsum of clipped transition ----
  if (tid < NN) {
    const float4* row = (const float4*)(trans + tid * NN);
    float s = 0.f;
    #pragma unroll 8
    for (int j = 0; j < NN / 4; ++j) {
      float4 v = row[j];
      s += fmaxf(v.x, EPSC) + fmaxf(v.y, EPSC) + fmaxf(v.z, EPSC) + fmaxf(v.w, EPSC);
    }
    red[tid] = 1.0f / s;
  }
  // ---- em chunk 0 -> embuf[0] ----
  {
    float4 v0 = em4[tid], v1 = em4[256 + tid];
    ((float4*)embuf[0])[tid] = v0;
    ((float4*)embuf[0])[256 + tid] = v1;
  }
  __syncthreads();

  // ---- forward fragment tf[k] = Tn[64h+k][n_own] (FULL unroll -> VGPRs) ----
  float tf[64];
  {
    const float* tcol = trans + 64 * h * NN + n_own;
    const float* rrow = red + 64 * h;
    #pragma unroll
    for (int k = 0; k < 64; ++k) tf[k] = fmaxf(tcol[k * NN], EPSC) * rrow[k];
  }

  // ---- alpha~_0 ----
  float2 pv = ((const float2*)prior)[lane];
  float p0v = fmaxf(pv.x, EPSC), p1v = fmaxf(pv.y, EPSC);
  float psum = p0v + p1v;
  #pragma unroll
  for (int m = 1; m < 64; m <<= 1) psum += __shfl_xor(psum, m, 64);
  const float pinv = rcpf(psum);
  float2 e0 = *(const float2*)&embuf[0][0][2 * lane];
  float a0 = p0v * pinv * __expf(e0.x);
  float a1 = p1v * pinv * __expf(e0.y);
  if (w == 0) *(float2*)&abuf[0][0][2 * lane] = make_float2(a0, a1);
  float2 em1 = *(const float2*)&embuf[0][1][2 * lane];
  float d0 = __expf(em1.x), d1 = __expf(em1.y);   // d_1
  float rinv_last = 1.f;

  // ================= forward =================
  for (int t = 1; t < TT; ++t) {
    if ((t & 15) == 15 && t < TT - 1) {           // load em chunk (t+1)/16
      const int c = (t + 1) >> 4;
      const float4* src = em4 + c * 512;
      float4* dst = (float4*)embuf[c & 1];
      float4 v0 = src[tid], v1 = src[256 + tid];
      dst[tid] = v0; dst[256 + tid] = v1;
    }
    const float c = (h == 0) ? dot_half<0>(tf, a0, a1) : dot_half<32>(tf, a0, a1);
    const int buf = t & 1;
    part[buf][pr_][h * 68 + lane] = c;
    __syncthreads();
    float2 pA = *(const float2*)&part[buf][ps][sl];
    float2 pB = *(const float2*)&part[buf][ps][68 + sl];
    const float raw0 = part[buf][0][0] + part[buf][0][68];
    const float rinv = rcpf(raw0);
    if (tid == 0) sarr[t] = rinv;
    rinv_last = rinv;
    a0 = (pA.x + pB.x) * (d0 * rinv);
    a1 = (pA.y + pB.y) * (d1 * rinv);
    if (w == 0 && t < TT - 1)
      *(float2*)&abuf[(t >> 4) & 1][t & 15][2 * lane] = make_float2(a0, a1);
    if ((t & 15) == 0) {                          // dump alpha chunk (t/16 - 1)
      const float4* src = (const float4*)abuf[((t >> 4) & 1) ^ 1];
      float4* dst = out4 + (t - 16) * (NN / 4);
      dst[tid] = src[tid]; dst[256 + tid] = src[256 + tid];
    }
    if (t < TT - 1) {                             // d_{t+1}, off-chain
      const int tn = t + 1;
      float2 emn = *(const float2*)&embuf[(tn >> 4) & 1][tn & 15][2 * lane];
      d0 = __expf(emn.x); d1 = __expf(emn.y);
    }
  }
  // here: d0,d1 = exp(em[511]); rinv_last = r_511; a = alpha~_511

  // ================= final softmax =================
  float tot = a0 + a1;
  #pragma unroll
  for (int m = 1; m < 64; m <<= 1) tot += __shfl_xor(tot, m, 64);
  const float it = rcpf(tot);
  const float P0f = a0 * it, P1f = a1 * it;       // p_511
  if (w == 0) *(float2*)&pbuf[1][15][2 * lane] = make_float2(P0f, P1f);
  // dump alpha chunk 31 (buffer 1), rows 496..511 (slot 15 garbage, later overwritten)
  {
    const float4* src = (const float4*)abuf[1];
    float4* dst = out4 + 496 * (NN / 4);
    dst[tid] = src[tid]; dst[256 + tid] = src[256 + tid];
  }

  // ---- backward fragment tb[k] = Tn[n_own][64h+k] (built now: tf dead soon) ----
  float tb[64];
  {
    const float inv = red[n_own];
    const float4* r = (const float4*)(trans + n_own * NN + 64 * h);
    #pragma unroll
    for (int k = 0; k < 16; ++k) {
      float4 v = r[k];
      tb[4*k+0] = fmaxf(v.x, EPSC) * inv;
      tb[4*k+1] = fmaxf(v.y, EPSC) * inv;
      tb[4*k+2] = fmaxf(v.z, EPSC) * inv;
      tb[4*k+3] = fmaxf(v.w, EPSC) * inv;
    }
  }

  // ---- backward init: q for step 510's dot; pipeline regs for t=510 ----
  float q0 = P0f * (d0 * rinv_last * rcpf(a0));
  float q1 = P1f * (d1 * rinv_last * rcpf(a1));
  float2 av  = *(const float2*)&abuf[1][14][2 * lane];   // alpha~_510
  float2 emv = *(const float2*)&embuf[1][14][2 * lane];  // em_510
  float db0 = __expf(emv.x), db1 = __expf(emv.y);
  float sr = sarr[510];

  // ================= backward =================
  for (int t = TT - 2; t >= 0; --t) {
    if ((t & 15) == 14 && t >= 30) {              // load em+alpha chunk (t/16 - 1)
      const int c = (t >> 4) - 1;
      const float4* esrc = em4 + c * 512;
      const float4* asrc = out4 + c * 512;
      float4* edst = (float4*)embuf[c & 1];
      float4* adst = (float4*)abuf[c & 1];
      float4 e0v = esrc[tid], e1v = esrc[256 + tid];
      float4 a0v = asrc[tid], a1v = asrc[256 + tid];
      edst[tid] = e0v; edst[256 + tid] = e1v;
      adst[tid] = a0v; adst[256 + tid] = a1v;
    }
    const float cc = (h == 0) ? dot_half<0>(tb, q0, q1) : dot_half<32>(tb, q0, q1);
    const int buf = t & 1;
    part[buf][pr_][h * 68 + lane] = cc;
    __syncthreads();
    float2 pA = *(const float2*)&part[buf][ps][sl];
    float2 pB = *(const float2*)&part[buf][ps][68 + sl];
    const float P0 = av.x * (pA.x + pB.x);        // p_t
    const float P1 = av.y * (pA.y + pB.y);
    if (w == 0) *(float2*)&pbuf[(t >> 4) & 1][t & 15][2 * lane] = make_float2(P0, P1);
    if ((t & 15) == 15) {                         // dump p chunk (t/16 + 1)
      const int ck = (t >> 4) + 1;
      const float4* src = (const float4*)pbuf[ck & 1];
      float4* dst = out4 + ck * 512;
      dst[tid] = src[tid]; dst[256 + tid] = src[256 + tid];
    }
    // q for next iteration: q = p_t * exp(em_t) * sarr[t] / alpha~_t
    const float g0 = db0 * sr * rcpf(av.x);
    const float g1 = db1 * sr * rcpf(av.y);
    q0 = P0 * g0; q1 = P1 * g1;
    if (t > 0) {                                  // pipeline regs for t-1 (off-chain)
      const int tp = t - 1;
      av = *(const float2*)&abuf[(tp >> 4) & 1][tp & 15][2 * lane];
      float2 e2 = *(const float2*)&embuf[(tp >> 4) & 1][tp & 15][2 * lane];
      db0 = __expf(e2.x); db1 = __expf(e2.y);
      sr = sarr[tp];
    }
  }
  __syncthreads();
  {
    const float4* src = (const float4*)pbuf[0];   // p chunk 0, rows 0..15
    float4* dst = out4;
    dst[tid] = src[tid]; dst[256 + tid] = src[256 + tid];
  }
}

extern "C" void kernel_launch(void* const* d_in, const int* in_sizes, int n_in,
                              void* d_out, int out_size, void* d_ws, size_t ws_size,
                              hipStream_t stream) {
  (void)in_sizes; (void)n_in; (void)d_ws; (void)ws_size; (void)out_size;
  const float* trans = (const float*)d_in[0];
  const float* emis  = (const float*)d_in[1];
  const float* prior = (const float*)d_in[2];
  float* out = (float*)d_out;
  soft_viterbi_kernel<<<dim3(BB), dim3(256), 0, stream>>>(trans, emis, prior, out);
}